// Round 3
// baseline (336.533 us; speedup 1.0000x reference)
//
#include <hip/hip_runtime.h>
#include <math.h>

#define QN 4096
#define NN 1024
#define FD 64
#define HD 128

// workspace layout (float offsets)
#define OFF_UT    0                      // U_T [128 h][4096 q]
#define OFF_B     524288                 // B   [1024 n][128 h]
#define OFF_L     655360                 // L   [1024 n][4096 q]
#define OFF_PM    4849664                // pm  [4096 q][64 ntile]
#define OFF_PART  5111808                // part[8 c][4096 q][64 f]
#define OFF_SPART 7208960                // spart[8 c][4096 q]
// end: 7241728 floats ~= 29.0 MB

// ---------------- K1: B[n,h], U_T[h,q] precompute ----------------
__global__ __launch_bounds__(256) void k1_prep(
    const float* __restrict__ qp, const float* __restrict__ nf,
    const float* __restrict__ npos, const float* __restrict__ aW1,
    const float* __restrict__ ab1, float* __restrict__ B, float* __restrict__ UT) {
  int idx = blockIdx.x * 256 + threadIdx.x;
  if (idx < QN * HD) {
    int h = idx >> 12, q = idx & 4095;      // U_T[h][q]
    UT[idx] = qp[q*3+0] * aW1[(FD+0)*HD + h]
            + qp[q*3+1] * aW1[(FD+1)*HD + h]
            + qp[q*3+2] * aW1[(FD+2)*HD + h];
  } else {
    int i2 = idx - QN * HD;
    if (i2 < NN * HD) {
      int n = i2 >> 7, h = i2 & 127;
      float s = ab1[h];
      #pragma unroll
      for (int f = 0; f < FD; ++f) s = fmaf(nf[n*FD+f], aW1[f*HD+h], s);
      s -= npos[n*3+0] * aW1[(FD+0)*HD + h]
         + npos[n*3+1] * aW1[(FD+1)*HD + h]
         + npos[n*3+2] * aW1[(FD+2)*HD + h];
      B[i2] = s;
    }
  }
}

// ---------------- K2: logits L[n][q] + per-tile max pm[q][ny] ----------------
// tile: 256 q x 16 n; 4 q/lane; wave w owns n-slice [w*4, w*4+4)
// grid (16, 64) = 1024 blocks = 4 blocks/CU = 4 waves/SIMD.

#define LOADU(dst, hcv) { \
  const float* up_ = uptr + (hcv)*8*QN; \
  _Pragma("unroll") for (int hh = 0; hh < 8; ++hh) \
    _Pragma("unroll") for (int qq = 0; qq < 4; ++qq) \
      dst[qq][hh] = up_[hh*QN + qq*64]; }

#define COMPUTE(u, hcv) { \
  float vv[8]; \
  _Pragma("unroll") for (int hh = 0; hh < 8; ++hh) vv[hh] = aW2[(hcv)*8 + hh]; \
  _Pragma("unroll") for (int nn = 0; nn < 4; ++nn) { \
    const float4* bp = (const float4*)(Bs + (nb + nn) * HD + (hcv)*8); \
    float4 b0 = bp[0], b1 = bp[1]; \
    float bb[8] = {b0.x,b0.y,b0.z,b0.w,b1.x,b1.y,b1.z,b1.w}; \
    _Pragma("unroll") for (int qq = 0; qq < 4; ++qq) \
      _Pragma("unroll") for (int hh = 0; hh < 8; ++hh) { \
        float r = fmaxf(bb[hh] + u[qq][hh], 0.f); \
        acc[qq][nn] = fmaf(r, vv[hh], acc[qq][nn]); } } }

__global__ __launch_bounds__(256, 4) void k2_logits(
    const float* __restrict__ Bg, const float* __restrict__ UT,
    const float* __restrict__ aW2, const float* __restrict__ ab2,
    const float* __restrict__ qp, const float* __restrict__ npos,
    float* __restrict__ L, float* __restrict__ pm) {
  __shared__ float Bs[16 * HD];      // 8 KB
  __shared__ float red[4][4][64];    // 4 KB
  const int q0 = blockIdx.x * 256, n0 = blockIdx.y * 16;
  const int t = threadIdx.x;
  {
    const float4* src = (const float4*)(Bg + n0 * HD);
    float4* dst = (float4*)Bs;
    #pragma unroll
    for (int r = 0; r < 2; ++r) dst[r*256 + t] = src[r*256 + t];
  }
  __syncthreads();
  const int lane = t & 63, w = t >> 6;
  const int nb = w * 4;
  const float* uptr = UT + q0 + lane;

  float acc[4][4];
  #pragma unroll
  for (int qq = 0; qq < 4; ++qq)
    #pragma unroll
    for (int nn = 0; nn < 4; ++nn) acc[qq][nn] = 0.f;

  float uA[4][8], uB[4][8];
  LOADU(uA, 0);
  #pragma unroll 1
  for (int hc = 0; hc < 14; hc += 2) {
    LOADU(uB, hc + 1);
    COMPUTE(uA, hc);
    LOADU(uA, hc + 2);
    COMPUTE(uB, hc + 1);
  }
  LOADU(uB, 15);
  COMPUTE(uA, 14);
  COMPUTE(uB, 15);

  const float bias2 = ab2[0];
  float qx[4], qy[4], m4[4];
  #pragma unroll
  for (int qq = 0; qq < 4; ++qq) {
    int q = q0 + qq*64 + lane;
    qx[qq] = qp[q*3+0];
    qy[qq] = qp[q*3+1];
    m4[qq] = -3.4e38f;
  }
  #pragma unroll
  for (int nn = 0; nn < 4; ++nn) {
    int n = n0 + nb + nn;
    float px = npos[n*3+0], py = npos[n*3+1];
    #pragma unroll
    for (int qq = 0; qq < 4; ++qq) {
      float dx = qx[qq] - px, dy = qy[qq] - py;
      float wgt = 1.f / (sqrtf(dx*dx + dy*dy) + 1e-6f);
      float lg = (acc[qq][nn] + bias2) * wgt;
      L[n * QN + q0 + qq*64 + lane] = lg;
      m4[qq] = fmaxf(m4[qq], lg);
    }
  }
  #pragma unroll
  for (int qq = 0; qq < 4; ++qq) red[w][qq][lane] = m4[qq];
  __syncthreads();
  {
    int qq = t >> 6, ll = t & 63;
    float mm = fmaxf(fmaxf(red[0][qq][ll], red[1][qq][ll]),
                     fmaxf(red[2][qq][ll], red[3][qq][ll]));
    pm[(q0 + qq*64 + ll) * 64 + blockIdx.y] = mm;
  }
}

// ---------------- K4: exp + partial aggregate; part[c][q][f] ----------------
__global__ __launch_bounds__(256) void k4_agg(
    const float* __restrict__ L, const float* __restrict__ pm,
    const float* __restrict__ nf, float* __restrict__ part,
    float* __restrict__ spart) {
  __shared__ float red[4][32][65];   // padded: no stride-64 bank conflicts
  __shared__ float sred[4][64];
  int b = blockIdx.x;
  int qt = b & 63, c = b >> 6;        // c in [0,8)
  int t = threadIdx.x, lane = t & 63, w = t >> 6;
  int q = qt * 64 + lane;

  float m = -3.4e38f;
  {
    const float4* pmq = (const float4*)(pm + q * 64);
    #pragma unroll
    for (int g = 0; g < 16; ++g) {
      float4 pv = pmq[g];
      m = fmaxf(m, fmaxf(fmaxf(pv.x, pv.y), fmaxf(pv.z, pv.w)));
    }
  }

  float acc[64];
  #pragma unroll
  for (int f = 0; f < 64; ++f) acc[f] = 0.f;
  float s = 0.f;

  int nbase = c * 128 + w * 32;
  for (int i = 0; i < 32; ++i) {
    int n = nbase + i;
    float p = exp2f((L[n * QN + q] - m) * 1.44269504088896f);
    s += p;
    const float4* nfr = (const float4*)(nf + n * FD);
    #pragma unroll
    for (int g = 0; g < 4; ++g) {
      float4 a0 = nfr[g*4+0], a1 = nfr[g*4+1], a2 = nfr[g*4+2], a3 = nfr[g*4+3];
      acc[g*16+ 0] = fmaf(p, a0.x, acc[g*16+ 0]);
      acc[g*16+ 1] = fmaf(p, a0.y, acc[g*16+ 1]);
      acc[g*16+ 2] = fmaf(p, a0.z, acc[g*16+ 2]);
      acc[g*16+ 3] = fmaf(p, a0.w, acc[g*16+ 3]);
      acc[g*16+ 4] = fmaf(p, a1.x, acc[g*16+ 4]);
      acc[g*16+ 5] = fmaf(p, a1.y, acc[g*16+ 5]);
      acc[g*16+ 6] = fmaf(p, a1.z, acc[g*16+ 6]);
      acc[g*16+ 7] = fmaf(p, a1.w, acc[g*16+ 7]);
      acc[g*16+ 8] = fmaf(p, a2.x, acc[g*16+ 8]);
      acc[g*16+ 9] = fmaf(p, a2.y, acc[g*16+ 9]);
      acc[g*16+10] = fmaf(p, a2.z, acc[g*16+10]);
      acc[g*16+11] = fmaf(p, a2.w, acc[g*16+11]);
      acc[g*16+12] = fmaf(p, a3.x, acc[g*16+12]);
      acc[g*16+13] = fmaf(p, a3.y, acc[g*16+13]);
      acc[g*16+14] = fmaf(p, a3.z, acc[g*16+14]);
      acc[g*16+15] = fmaf(p, a3.w, acc[g*16+15]);
    }
  }

  sred[w][lane] = s;
  // pass 0: f in [0,32)
  #pragma unroll
  for (int f = 0; f < 32; ++f) red[w][f][lane] = acc[f];
  __syncthreads();
  for (int idx = t; idx < 2048; idx += 256) {
    int qq = idx >> 5, fr = idx & 31;
    float sum = red[0][fr][qq] + red[1][fr][qq] + red[2][fr][qq] + red[3][fr][qq];
    part[(c * QN + qt*64 + qq) * 64 + fr] = sum;
  }
  __syncthreads();
  // pass 1: f in [32,64)
  #pragma unroll
  for (int f = 0; f < 32; ++f) red[w][f][lane] = acc[32 + f];
  __syncthreads();
  for (int idx = t; idx < 2048; idx += 256) {
    int qq = idx >> 5, fr = idx & 31;
    float sum = red[0][fr][qq] + red[1][fr][qq] + red[2][fr][qq] + red[3][fr][qq];
    part[(c * QN + qt*64 + qq) * 64 + 32 + fr] = sum;
  }
  __syncthreads();
  if (t < 64) {
    spart[c * QN + qt*64 + t] = sred[0][t] + sred[1][t] + sred[2][t] + sred[3][t];
  }
}

// ---------------- K5: reduce partials, normalize, decode ----------------
// 256 blocks x 16 q; coalesced part reads (lanes span f).
__global__ __launch_bounds__(256) void k5_dec(
    const float* __restrict__ part, const float* __restrict__ spart,
    const float* __restrict__ dW1, const float* __restrict__ db1,
    const float* __restrict__ dW2, const float* __restrict__ db2,
    float* __restrict__ out) {
  __shared__ float agg[16][64];
  __shared__ float inv[16];
  __shared__ float h1s[16][128];
  int t = threadIdx.x;
  int qb = blockIdx.x * 16;
  if (t < 16) {
    float s = 0.f;
    #pragma unroll
    for (int c = 0; c < 8; ++c) s += spart[c*QN + qb + t];
    inv[t] = 1.f / s;
  }
  {
    int f = t & 63, qh = t >> 6;
    #pragma unroll
    for (int pass = 0; pass < 4; ++pass) {
      int qs = pass*4 + qh;
      float v = 0.f;
      #pragma unroll
      for (int c = 0; c < 8; ++c) v += part[(c*QN + qb + qs)*64 + f];
      agg[qs][f] = v;
    }
  }
  __syncthreads();
  {
    int h = t & 127, qg = t >> 7;
    #pragma unroll
    for (int k = 0; k < 8; ++k) {
      int qs = qg*8 + k;
      float a = 0.f;
      #pragma unroll
      for (int f = 0; f < 64; ++f) a = fmaf(agg[qs][f], dW1[f*HD + h], a);
      h1s[qs][h] = fmaxf(a * inv[qs] + db1[h], 0.f);
    }
  }
  __syncthreads();
  if (t < 48) {
    int qs = t / 3, o = t % 3;
    float a = db2[o];
    #pragma unroll
    for (int h = 0; h < HD; ++h) a = fmaf(h1s[qs][h], dW2[h*3 + o], a);
    out[(qb + qs)*3 + o] = a;
  }
}

extern "C" void kernel_launch(void* const* d_in, const int* in_sizes, int n_in,
                              void* d_out, int out_size, void* d_ws, size_t ws_size,
                              hipStream_t stream) {
  const float* qp   = (const float*)d_in[0];
  const float* nf   = (const float*)d_in[1];
  const float* npos = (const float*)d_in[2];
  const float* aW1  = (const float*)d_in[3];
  const float* ab1  = (const float*)d_in[4];
  const float* aW2  = (const float*)d_in[5];
  const float* ab2  = (const float*)d_in[6];
  const float* dW1  = (const float*)d_in[7];
  const float* db1  = (const float*)d_in[8];
  const float* dW2  = (const float*)d_in[9];
  const float* db2  = (const float*)d_in[10];

  float* ws    = (float*)d_ws;
  float* UT    = ws + OFF_UT;
  float* B     = ws + OFF_B;
  float* L     = ws + OFF_L;
  float* pm    = ws + OFF_PM;
  float* part  = ws + OFF_PART;
  float* spart = ws + OFF_SPART;

  hipLaunchKernelGGL(k1_prep, dim3(2560), dim3(256), 0, stream,
                     qp, nf, npos, aW1, ab1, B, UT);
  hipLaunchKernelGGL(k2_logits, dim3(16, 64), dim3(256), 0, stream,
                     B, UT, aW2, ab2, qp, npos, L, pm);
  hipLaunchKernelGGL(k4_agg, dim3(512), dim3(256), 0, stream, L, pm, nf, part, spart);
  hipLaunchKernelGGL(k5_dec, dim3(256), dim3(256), 0, stream,
                     part, spart, dW1, db1, dW2, db2, (float*)d_out);
}

// Round 4
// 119.398 us; speedup vs baseline: 2.8186x; 2.8186x over previous
//
#include <hip/hip_runtime.h>
#include <math.h>

#define QN 4096
#define NN 1024
#define FD 64
#define HD 128

typedef float v2f __attribute__((ext_vector_type(2)));

// workspace layout (float offsets)
#define OFF_UT2   0                      // UT2 [64 h2][4096 q][2]
#define OFF_B     524288                 // B   [1024 n][128 h]
#define OFF_VU    655360                 // vu  [4096 q]
#define OFF_VB    659456                 // vb  [1024 n]
#define OFF_L     660480                 // L   [1024 n][4096 q]
#define OFF_PM    4854784                // pm  [64 tile][4096 q]
#define OFF_PART  5116928                // part[8 c][4096 q][64 f]
#define OFF_SPART 7214080                // spart[8 c][4096 q]
// end: 7246848 floats = 29.0 MB

// ---------------- K0: fused prep: UT2, B, vb, vu ----------------
__global__ __launch_bounds__(256) void k0_prep(
    const float* __restrict__ qp, const float* __restrict__ nf,
    const float* __restrict__ npos, const float* __restrict__ aW1,
    const float* __restrict__ ab1, const float* __restrict__ aW2,
    float* __restrict__ B, float* __restrict__ UT2,
    float* __restrict__ vu, float* __restrict__ vb) {
  int bid = blockIdx.x, t = threadIdx.x;
  if (bid < 2048) {
    // UT2[h2][q][e]: flat idx = h2*8192 + q*2 + e
    int idx = bid * 256 + t;
    int e = idx & 1, q = (idx >> 1) & 4095, h2 = idx >> 13;
    int h = h2 * 2 + e;
    float u = qp[q*3+0] * aW1[(FD+0)*HD + h]
            + qp[q*3+1] * aW1[(FD+1)*HD + h]
            + qp[q*3+2] * aW1[(FD+2)*HD + h];
    UT2[idx] = u;
  } else if (bid < 2560) {
    // B[n][h] + vb[n] = sum_h aW2[h]*B[n][h]
    int i2 = (bid - 2048) * 256 + t;
    int n = i2 >> 7, h = i2 & 127;
    float s = ab1[h];
    #pragma unroll
    for (int f = 0; f < FD; ++f) s = fmaf(nf[n*FD+f], aW1[f*HD+h], s);
    s -= npos[n*3+0] * aW1[(FD+0)*HD + h]
       + npos[n*3+1] * aW1[(FD+1)*HD + h]
       + npos[n*3+2] * aW1[(FD+2)*HD + h];
    B[i2] = s;
    float pv = s * aW2[h];
    #pragma unroll
    for (int m = 1; m < 64; m <<= 1) pv += __shfl_xor(pv, m, 64);
    __shared__ float ps[4];
    if ((t & 63) == 0) ps[t >> 6] = pv;
    __syncthreads();
    if (t == 0)   vb[n] = ps[0] + ps[1];
    if (t == 128) vb[n] = ps[2] + ps[3];
  } else {
    // vu[q] = sum_h aW2[h] * u[q][h] (recompute u; no dependency)
    int q = (bid - 2560) * 256 + t;
    float q0 = qp[q*3+0], q1 = qp[q*3+1], q2 = qp[q*3+2];
    float acc = 0.f;
    #pragma unroll
    for (int h = 0; h < HD; ++h) {
      float u = q0 * aW1[(FD+0)*HD + h]
              + q1 * aW1[(FD+1)*HD + h]
              + q2 * aW1[(FD+2)*HD + h];
      acc = fmaf(aW2[h], u, acc);
    }
    vu[q] = acc;
  }
}

// ---------------- K2: logits; no LDS in hot loop ----------------
// tile 256q x 16n; 4 q/lane; wave w -> n-slice [w*4, w*4+4)
// score = 0.5*(vu[q]+vb[n]+sum_h v_h*|b+u|) + ab2; logit = score*w

#define LOADU(dst, hcv) { \
  _Pragma("unroll") for (int hp = 0; hp < 4; ++hp) { \
    const v2f* up_ = (const v2f*)UT2 + ((hcv)*4 + hp) * QN + q0 + lane; \
    _Pragma("unroll") for (int qq = 0; qq < 4; ++qq) \
      dst[qq][hp] = up_[qq*64]; } }

#define COMPUTE(u2, hcv) { \
  v2f vv[4]; \
  _Pragma("unroll") for (int hp = 0; hp < 4; ++hp) \
    vv[hp] = ((const v2f*)aW2)[(hcv)*4 + hp]; \
  _Pragma("unroll") for (int nn = 0; nn < 4; ++nn) { \
    const v2f* bp = (const v2f*)(Bg + (n0 + nb + nn) * HD + (hcv)*8); \
    v2f b0 = bp[0], b1 = bp[1], b2 = bp[2], b3 = bp[3]; \
    _Pragma("unroll") for (int qq = 0; qq < 4; ++qq) { \
      v2f t0 = u2[qq][0] + b0; \
      v2f t1 = u2[qq][1] + b1; \
      v2f t2 = u2[qq][2] + b2; \
      v2f t3 = u2[qq][3] + b3; \
      float a = acc[qq][nn]; \
      a = fmaf(vv[0].x, __builtin_fabsf(t0.x), a); \
      a = fmaf(vv[0].y, __builtin_fabsf(t0.y), a); \
      a = fmaf(vv[1].x, __builtin_fabsf(t1.x), a); \
      a = fmaf(vv[1].y, __builtin_fabsf(t1.y), a); \
      a = fmaf(vv[2].x, __builtin_fabsf(t2.x), a); \
      a = fmaf(vv[2].y, __builtin_fabsf(t2.y), a); \
      a = fmaf(vv[3].x, __builtin_fabsf(t3.x), a); \
      a = fmaf(vv[3].y, __builtin_fabsf(t3.y), a); \
      acc[qq][nn] = a; } } }

__global__ __launch_bounds__(256) void k2_logits(
    const float* __restrict__ Bg, const float* __restrict__ UT2,
    const float* __restrict__ aW2, const float* __restrict__ ab2,
    const float* __restrict__ qp, const float* __restrict__ npos,
    const float* __restrict__ vu, const float* __restrict__ vb,
    float* __restrict__ L, float* __restrict__ pm) {
  __shared__ float red[4][4][64];    // epilogue max-reduce only
  const int q0 = blockIdx.x * 256, n0 = blockIdx.y * 16;
  const int t = threadIdx.x;
  const int lane = t & 63, w = t >> 6;
  const int nb = w * 4;

  float acc[4][4];
  #pragma unroll
  for (int qq = 0; qq < 4; ++qq)
    #pragma unroll
    for (int nn = 0; nn < 4; ++nn) acc[qq][nn] = 0.f;

  v2f uA[4][4], uB[4][4];
  LOADU(uA, 0);
  #pragma unroll 1
  for (int hc = 0; hc < 14; hc += 2) {
    LOADU(uB, hc + 1);
    COMPUTE(uA, hc);
    LOADU(uA, hc + 2);
    COMPUTE(uB, hc + 1);
  }
  LOADU(uB, 15);
  COMPUTE(uA, 14);
  COMPUTE(uB, 15);

  const float bias2 = ab2[0];
  float qx[4], qy[4], vuq[4], m4[4];
  #pragma unroll
  for (int qq = 0; qq < 4; ++qq) {
    int q = q0 + qq*64 + lane;
    qx[qq] = qp[q*3+0];
    qy[qq] = qp[q*3+1];
    vuq[qq] = vu[q];
    m4[qq] = -3.4e38f;
  }
  #pragma unroll
  for (int nn = 0; nn < 4; ++nn) {
    int n = n0 + nb + nn;
    float px = npos[n*3+0], py = npos[n*3+1];
    float vbn = vb[n];
    #pragma unroll
    for (int qq = 0; qq < 4; ++qq) {
      float dx = qx[qq] - px, dy = qy[qq] - py;
      float wgt = 1.f / (sqrtf(dx*dx + dy*dy) + 1e-6f);
      float score = fmaf(0.5f, vuq[qq] + vbn + acc[qq][nn], bias2);
      float lg = score * wgt;
      L[n * QN + q0 + qq*64 + lane] = lg;
      m4[qq] = fmaxf(m4[qq], lg);
    }
  }
  #pragma unroll
  for (int qq = 0; qq < 4; ++qq) red[w][qq][lane] = m4[qq];
  __syncthreads();
  {
    int qq = t >> 6, ll = t & 63;
    float mm = fmaxf(fmaxf(red[0][qq][ll], red[1][qq][ll]),
                     fmaxf(red[2][qq][ll], red[3][qq][ll]));
    pm[blockIdx.y * QN + q0 + qq*64 + ll] = mm;   // coalesced
  }
}

// ---------------- K4: exp + partial aggregate; part[c][q][f] ----------------
__global__ __launch_bounds__(256) void k4_agg(
    const float* __restrict__ L, const float* __restrict__ pm,
    const float* __restrict__ nf, float* __restrict__ part,
    float* __restrict__ spart) {
  __shared__ float red[4][32][65];
  __shared__ float sred[4][64];
  int b = blockIdx.x;
  int qt = b & 63, c = b >> 6;        // c in [0,8)
  int t = threadIdx.x, lane = t & 63, w = t >> 6;
  int q = qt * 64 + lane;

  float m = -3.4e38f;
  #pragma unroll
  for (int c64 = 0; c64 < 64; ++c64) m = fmaxf(m, pm[c64 * QN + q]);

  float acc[64];
  #pragma unroll
  for (int f = 0; f < 64; ++f) acc[f] = 0.f;
  float s = 0.f;

  int nbase = c * 128 + w * 32;
  float cur = L[nbase * QN + q];
  for (int i = 0; i < 32; ++i) {
    int n = nbase + i;
    float nxt = (i < 31) ? L[(n + 1) * QN + q] : 0.f;
    float p = exp2f((cur - m) * 1.44269504088896f);
    s += p;
    const float4* nfr = (const float4*)(nf + n * FD);
    #pragma unroll
    for (int g = 0; g < 4; ++g) {
      float4 a0 = nfr[g*4+0], a1 = nfr[g*4+1], a2 = nfr[g*4+2], a3 = nfr[g*4+3];
      acc[g*16+ 0] = fmaf(p, a0.x, acc[g*16+ 0]);
      acc[g*16+ 1] = fmaf(p, a0.y, acc[g*16+ 1]);
      acc[g*16+ 2] = fmaf(p, a0.z, acc[g*16+ 2]);
      acc[g*16+ 3] = fmaf(p, a0.w, acc[g*16+ 3]);
      acc[g*16+ 4] = fmaf(p, a1.x, acc[g*16+ 4]);
      acc[g*16+ 5] = fmaf(p, a1.y, acc[g*16+ 5]);
      acc[g*16+ 6] = fmaf(p, a1.z, acc[g*16+ 6]);
      acc[g*16+ 7] = fmaf(p, a1.w, acc[g*16+ 7]);
      acc[g*16+ 8] = fmaf(p, a2.x, acc[g*16+ 8]);
      acc[g*16+ 9] = fmaf(p, a2.y, acc[g*16+ 9]);
      acc[g*16+10] = fmaf(p, a2.z, acc[g*16+10]);
      acc[g*16+11] = fmaf(p, a2.w, acc[g*16+11]);
      acc[g*16+12] = fmaf(p, a3.x, acc[g*16+12]);
      acc[g*16+13] = fmaf(p, a3.y, acc[g*16+13]);
      acc[g*16+14] = fmaf(p, a3.z, acc[g*16+14]);
      acc[g*16+15] = fmaf(p, a3.w, acc[g*16+15]);
    }
    cur = nxt;
  }

  sred[w][lane] = s;
  #pragma unroll
  for (int f = 0; f < 32; ++f) red[w][f][lane] = acc[f];
  __syncthreads();
  for (int idx = t; idx < 2048; idx += 256) {
    int qq = idx >> 5, fr = idx & 31;
    float sum = red[0][fr][qq] + red[1][fr][qq] + red[2][fr][qq] + red[3][fr][qq];
    part[(c * QN + qt*64 + qq) * 64 + fr] = sum;
  }
  __syncthreads();
  #pragma unroll
  for (int f = 0; f < 32; ++f) red[w][f][lane] = acc[32 + f];
  __syncthreads();
  for (int idx = t; idx < 2048; idx += 256) {
    int qq = idx >> 5, fr = idx & 31;
    float sum = red[0][fr][qq] + red[1][fr][qq] + red[2][fr][qq] + red[3][fr][qq];
    part[(c * QN + qt*64 + qq) * 64 + 32 + fr] = sum;
  }
  __syncthreads();
  if (t < 64) {
    spart[c * QN + qt*64 + t] = sred[0][t] + sred[1][t] + sred[2][t] + sred[3][t];
  }
}

// ---------------- K5: reduce partials, normalize, decode ----------------
__global__ __launch_bounds__(256) void k5_dec(
    const float* __restrict__ part, const float* __restrict__ spart,
    const float* __restrict__ dW1, const float* __restrict__ db1,
    const float* __restrict__ dW2, const float* __restrict__ db2,
    float* __restrict__ out) {
  __shared__ float agg[16][64];
  __shared__ float inv[16];
  __shared__ float h1s[16][128];
  int t = threadIdx.x;
  int qb = blockIdx.x * 16;
  if (t < 16) {
    float s = 0.f;
    #pragma unroll
    for (int c = 0; c < 8; ++c) s += spart[c*QN + qb + t];
    inv[t] = 1.f / s;
  }
  {
    int f = t & 63, qh = t >> 6;
    #pragma unroll
    for (int pass = 0; pass < 4; ++pass) {
      int qs = pass*4 + qh;
      float v = 0.f;
      #pragma unroll
      for (int c = 0; c < 8; ++c) v += part[(c*QN + qb + qs)*64 + f];
      agg[qs][f] = v;
    }
  }
  __syncthreads();
  {
    int h = t & 127, qg = t >> 7;
    #pragma unroll
    for (int k = 0; k < 8; ++k) {
      int qs = qg*8 + k;
      float a = 0.f;
      #pragma unroll
      for (int f = 0; f < 64; ++f) a = fmaf(agg[qs][f], dW1[f*HD + h], a);
      h1s[qs][h] = fmaxf(a * inv[qs] + db1[h], 0.f);
    }
  }
  __syncthreads();
  if (t < 48) {
    int qs = t / 3, o = t % 3;
    float a = db2[o];
    #pragma unroll
    for (int h = 0; h < HD; ++h) a = fmaf(h1s[qs][h], dW2[h*3 + o], a);
    out[(qb + qs)*3 + o] = a;
  }
}

extern "C" void kernel_launch(void* const* d_in, const int* in_sizes, int n_in,
                              void* d_out, int out_size, void* d_ws, size_t ws_size,
                              hipStream_t stream) {
  const float* qp   = (const float*)d_in[0];
  const float* nf   = (const float*)d_in[1];
  const float* npos = (const float*)d_in[2];
  const float* aW1  = (const float*)d_in[3];
  const float* ab1  = (const float*)d_in[4];
  const float* aW2  = (const float*)d_in[5];
  const float* ab2  = (const float*)d_in[6];
  const float* dW1  = (const float*)d_in[7];
  const float* db1  = (const float*)d_in[8];
  const float* dW2  = (const float*)d_in[9];
  const float* db2  = (const float*)d_in[10];

  float* ws    = (float*)d_ws;
  float* UT2   = ws + OFF_UT2;
  float* B     = ws + OFF_B;
  float* vu    = ws + OFF_VU;
  float* vb    = ws + OFF_VB;
  float* L     = ws + OFF_L;
  float* pm    = ws + OFF_PM;
  float* part  = ws + OFF_PART;
  float* spart = ws + OFF_SPART;

  hipLaunchKernelGGL(k0_prep, dim3(2576), dim3(256), 0, stream,
                     qp, nf, npos, aW1, ab1, aW2, B, UT2, vu, vb);
  hipLaunchKernelGGL(k2_logits, dim3(16, 64), dim3(256), 0, stream,
                     B, UT2, aW2, ab2, qp, npos, vu, vb, L, pm);
  hipLaunchKernelGGL(k4_agg, dim3(512), dim3(256), 0, stream, L, pm, nf, part, spart);
  hipLaunchKernelGGL(k5_dec, dim3(256), dim3(256), 0, stream,
                     part, spart, dW1, db1, dW2, db2, (float*)d_out);
}

// Round 5
// 106.368 us; speedup vs baseline: 3.1639x; 1.1225x over previous
//
#include <hip/hip_runtime.h>
#include <math.h>

#define QN 4096
#define NN 1024
#define FD 64
#define HD 128

typedef float v2f __attribute__((ext_vector_type(2)));

// workspace layout (float offsets)
#define OFF_UT2   0                      // UT2 [64 h2][4096 q][2]
#define OFF_B     524288                 // B   [1024 n][128 h]
#define OFF_VU    655360                 // vu  [4096 q]
#define OFF_VB    659456                 // vb  [1024 n]
#define OFF_L     660480                 // L   [1024 n][4096 q]
#define OFF_PM    4854784                // pm  [64 tile][4096 q]
#define OFF_PART  5116928                // part[8 c][4096 q][64 f]
#define OFF_SPART 7214080                // spart[8 c][4096 q]
// end: 7246848 floats = 29.0 MB

// ---------------- K0: fused prep: UT2, B, vb, vu ----------------
__global__ __launch_bounds__(256) void k0_prep(
    const float* __restrict__ qp, const float* __restrict__ nf,
    const float* __restrict__ npos, const float* __restrict__ aW1,
    const float* __restrict__ ab1, const float* __restrict__ aW2,
    float* __restrict__ B, float* __restrict__ UT2,
    float* __restrict__ vu, float* __restrict__ vb) {
  int bid = blockIdx.x, t = threadIdx.x;
  if (bid < 2048) {
    int idx = bid * 256 + t;
    int e = idx & 1, q = (idx >> 1) & 4095, h2 = idx >> 13;
    int h = h2 * 2 + e;
    float u = qp[q*3+0] * aW1[(FD+0)*HD + h]
            + qp[q*3+1] * aW1[(FD+1)*HD + h]
            + qp[q*3+2] * aW1[(FD+2)*HD + h];
    UT2[idx] = u;
  } else if (bid < 2560) {
    int i2 = (bid - 2048) * 256 + t;
    int n = i2 >> 7, h = i2 & 127;
    float s = ab1[h];
    #pragma unroll
    for (int f = 0; f < FD; ++f) s = fmaf(nf[n*FD+f], aW1[f*HD+h], s);
    s -= npos[n*3+0] * aW1[(FD+0)*HD + h]
       + npos[n*3+1] * aW1[(FD+1)*HD + h]
       + npos[n*3+2] * aW1[(FD+2)*HD + h];
    B[i2] = s;
    float pv = s * aW2[h];
    #pragma unroll
    for (int m = 1; m < 64; m <<= 1) pv += __shfl_xor(pv, m, 64);
    __shared__ float ps[4];
    if ((t & 63) == 0) ps[t >> 6] = pv;
    __syncthreads();
    if (t == 0)   vb[n] = ps[0] + ps[1];
    if (t == 128) vb[n] = ps[2] + ps[3];
  } else {
    int q = (bid - 2560) * 256 + t;
    float q0 = qp[q*3+0], q1 = qp[q*3+1], q2 = qp[q*3+2];
    float acc = 0.f;
    #pragma unroll
    for (int h = 0; h < HD; ++h) {
      float u = q0 * aW1[(FD+0)*HD + h]
              + q1 * aW1[(FD+1)*HD + h]
              + q2 * aW1[(FD+2)*HD + h];
      acc = fmaf(aW2[h], u, acc);
    }
    vu[q] = acc;
  }
}

// ---------------- K2: logits; LDS-staged B + reg-prefetched U + abs-trick ----
// tile 256q x 16n; 4 q/lane; wave w -> n-slice [w*4, w*4+4)
// score = 0.5*(vu[q]+vb[n]+sum_h v_h*|b+u|) + ab2; logit = score*w

#define LOADU(dst, hcv) { \
  _Pragma("unroll") for (int hp = 0; hp < 4; ++hp) { \
    const v2f* up_ = (const v2f*)UT2 + ((hcv)*4 + hp) * QN + q0 + lane; \
    _Pragma("unroll") for (int qq = 0; qq < 4; ++qq) \
      dst[qq][hp] = up_[qq*64]; } }

#define COMPUTE(u2, hcv) { \
  v2f vv[4]; \
  _Pragma("unroll") for (int hp = 0; hp < 4; ++hp) \
    vv[hp] = ((const v2f*)aW2)[(hcv)*4 + hp]; \
  _Pragma("unroll") for (int nn = 0; nn < 4; ++nn) { \
    const v2f* bp = (const v2f*)(Bs + (nb + nn) * HD + (hcv)*8); \
    v2f b0 = bp[0], b1 = bp[1], b2 = bp[2], b3 = bp[3]; \
    _Pragma("unroll") for (int qq = 0; qq < 4; ++qq) { \
      v2f t0 = u2[qq][0] + b0; \
      v2f t1 = u2[qq][1] + b1; \
      v2f t2 = u2[qq][2] + b2; \
      v2f t3 = u2[qq][3] + b3; \
      float a = acc[qq][nn]; \
      a = fmaf(vv[0].x, __builtin_fabsf(t0.x), a); \
      a = fmaf(vv[0].y, __builtin_fabsf(t0.y), a); \
      a = fmaf(vv[1].x, __builtin_fabsf(t1.x), a); \
      a = fmaf(vv[1].y, __builtin_fabsf(t1.y), a); \
      a = fmaf(vv[2].x, __builtin_fabsf(t2.x), a); \
      a = fmaf(vv[2].y, __builtin_fabsf(t2.y), a); \
      a = fmaf(vv[3].x, __builtin_fabsf(t3.x), a); \
      a = fmaf(vv[3].y, __builtin_fabsf(t3.y), a); \
      acc[qq][nn] = a; } } }

__global__ __launch_bounds__(256) void k2_logits(
    const float* __restrict__ Bg, const float* __restrict__ UT2,
    const float* __restrict__ aW2, const float* __restrict__ ab2,
    const float* __restrict__ qp, const float* __restrict__ npos,
    const float* __restrict__ vu, const float* __restrict__ vb,
    float* __restrict__ L, float* __restrict__ pm) {
  __shared__ float Bs[16 * HD];      // 8 KB
  __shared__ float red[4][4][64];    // 4 KB
  const int q0 = blockIdx.x * 256, n0 = blockIdx.y * 16;
  const int t = threadIdx.x;
  {
    const float4* src = (const float4*)(Bg + n0 * HD);
    float4* dst = (float4*)Bs;
    #pragma unroll
    for (int r = 0; r < 2; ++r) dst[r*256 + t] = src[r*256 + t];
  }
  __syncthreads();
  const int lane = t & 63, w = t >> 6;
  const int nb = w * 4;

  float acc[4][4];
  #pragma unroll
  for (int qq = 0; qq < 4; ++qq)
    #pragma unroll
    for (int nn = 0; nn < 4; ++nn) acc[qq][nn] = 0.f;

  v2f uA[4][4], uB[4][4];
  LOADU(uA, 0);
  #pragma unroll 1
  for (int hc = 0; hc < 14; hc += 2) {
    LOADU(uB, hc + 1);
    COMPUTE(uA, hc);
    LOADU(uA, hc + 2);
    COMPUTE(uB, hc + 1);
  }
  LOADU(uB, 15);
  COMPUTE(uA, 14);
  COMPUTE(uB, 15);

  const float bias2 = ab2[0];
  float qx[4], qy[4], vuq[4], m4[4];
  #pragma unroll
  for (int qq = 0; qq < 4; ++qq) {
    int q = q0 + qq*64 + lane;
    qx[qq] = qp[q*3+0];
    qy[qq] = qp[q*3+1];
    vuq[qq] = vu[q];
    m4[qq] = -3.4e38f;
  }
  #pragma unroll
  for (int nn = 0; nn < 4; ++nn) {
    int n = n0 + nb + nn;
    float px = npos[n*3+0], py = npos[n*3+1];
    float vbn = vb[n];
    #pragma unroll
    for (int qq = 0; qq < 4; ++qq) {
      float dx = qx[qq] - px, dy = qy[qq] - py;
      float wgt = 1.f / (sqrtf(dx*dx + dy*dy) + 1e-6f);
      float score = fmaf(0.5f, vuq[qq] + vbn + acc[qq][nn], bias2);
      float lg = score * wgt;
      L[n * QN + q0 + qq*64 + lane] = lg;
      m4[qq] = fmaxf(m4[qq], lg);
    }
  }
  #pragma unroll
  for (int qq = 0; qq < 4; ++qq) red[w][qq][lane] = m4[qq];
  __syncthreads();
  {
    int qq = t >> 6, ll = t & 63;
    float mm = fmaxf(fmaxf(red[0][qq][ll], red[1][qq][ll]),
                     fmaxf(red[2][qq][ll], red[3][qq][ll]));
    pm[blockIdx.y * QN + q0 + qq*64 + ll] = mm;
  }
}

// ---------------- K4: exp + partial aggregate; part[c][q][f] ----------------
__global__ __launch_bounds__(256) void k4_agg(
    const float* __restrict__ L, const float* __restrict__ pm,
    const float* __restrict__ nf, float* __restrict__ part,
    float* __restrict__ spart) {
  __shared__ float red[4][32][65];
  __shared__ float sred[4][64];
  int b = blockIdx.x;
  int qt = b & 63, c = b >> 6;        // c in [0,8)
  int t = threadIdx.x, lane = t & 63, w = t >> 6;
  int q = qt * 64 + lane;

  float m = -3.4e38f;
  #pragma unroll
  for (int c64 = 0; c64 < 64; ++c64) m = fmaxf(m, pm[c64 * QN + q]);

  float acc[64];
  #pragma unroll
  for (int f = 0; f < 64; ++f) acc[f] = 0.f;
  float s = 0.f;

  int nbase = c * 128 + w * 32;
  float cur = L[nbase * QN + q];
  for (int i = 0; i < 32; ++i) {
    int n = nbase + i;
    float nxt = (i < 31) ? L[(n + 1) * QN + q] : 0.f;
    float p = exp2f((cur - m) * 1.44269504088896f);
    s += p;
    const float4* nfr = (const float4*)(nf + n * FD);
    #pragma unroll
    for (int g = 0; g < 4; ++g) {
      float4 a0 = nfr[g*4+0], a1 = nfr[g*4+1], a2 = nfr[g*4+2], a3 = nfr[g*4+3];
      acc[g*16+ 0] = fmaf(p, a0.x, acc[g*16+ 0]);
      acc[g*16+ 1] = fmaf(p, a0.y, acc[g*16+ 1]);
      acc[g*16+ 2] = fmaf(p, a0.z, acc[g*16+ 2]);
      acc[g*16+ 3] = fmaf(p, a0.w, acc[g*16+ 3]);
      acc[g*16+ 4] = fmaf(p, a1.x, acc[g*16+ 4]);
      acc[g*16+ 5] = fmaf(p, a1.y, acc[g*16+ 5]);
      acc[g*16+ 6] = fmaf(p, a1.z, acc[g*16+ 6]);
      acc[g*16+ 7] = fmaf(p, a1.w, acc[g*16+ 7]);
      acc[g*16+ 8] = fmaf(p, a2.x, acc[g*16+ 8]);
      acc[g*16+ 9] = fmaf(p, a2.y, acc[g*16+ 9]);
      acc[g*16+10] = fmaf(p, a2.z, acc[g*16+10]);
      acc[g*16+11] = fmaf(p, a2.w, acc[g*16+11]);
      acc[g*16+12] = fmaf(p, a3.x, acc[g*16+12]);
      acc[g*16+13] = fmaf(p, a3.y, acc[g*16+13]);
      acc[g*16+14] = fmaf(p, a3.z, acc[g*16+14]);
      acc[g*16+15] = fmaf(p, a3.w, acc[g*16+15]);
    }
    cur = nxt;
  }

  sred[w][lane] = s;
  #pragma unroll
  for (int f = 0; f < 32; ++f) red[w][f][lane] = acc[f];
  __syncthreads();
  for (int idx = t; idx < 2048; idx += 256) {
    int qq = idx >> 5, fr = idx & 31;
    float sum = red[0][fr][qq] + red[1][fr][qq] + red[2][fr][qq] + red[3][fr][qq];
    part[(c * QN + qt*64 + qq) * 64 + fr] = sum;
  }
  __syncthreads();
  #pragma unroll
  for (int f = 0; f < 32; ++f) red[w][f][lane] = acc[32 + f];
  __syncthreads();
  for (int idx = t; idx < 2048; idx += 256) {
    int qq = idx >> 5, fr = idx & 31;
    float sum = red[0][fr][qq] + red[1][fr][qq] + red[2][fr][qq] + red[3][fr][qq];
    part[(c * QN + qt*64 + qq) * 64 + 32 + fr] = sum;
  }
  __syncthreads();
  if (t < 64) {
    spart[c * QN + qt*64 + t] = sred[0][t] + sred[1][t] + sred[2][t] + sred[3][t];
  }
}

// ---------------- K5: reduce partials, normalize, decode ----------------
__global__ __launch_bounds__(256) void k5_dec(
    const float* __restrict__ part, const float* __restrict__ spart,
    const float* __restrict__ dW1, const float* __restrict__ db1,
    const float* __restrict__ dW2, const float* __restrict__ db2,
    float* __restrict__ out) {
  __shared__ float agg[16][64];
  __shared__ float inv[16];
  __shared__ float h1s[16][128];
  int t = threadIdx.x;
  int qb = blockIdx.x * 16;
  if (t < 16) {
    float s = 0.f;
    #pragma unroll
    for (int c = 0; c < 8; ++c) s += spart[c*QN + qb + t];
    inv[t] = 1.f / s;
  }
  {
    int f = t & 63, qh = t >> 6;
    #pragma unroll
    for (int pass = 0; pass < 4; ++pass) {
      int qs = pass*4 + qh;
      float v = 0.f;
      #pragma unroll
      for (int c = 0; c < 8; ++c) v += part[(c*QN + qb + qs)*64 + f];
      agg[qs][f] = v;
    }
  }
  __syncthreads();
  {
    int h = t & 127, qg = t >> 7;
    #pragma unroll
    for (int k = 0; k < 8; ++k) {
      int qs = qg*8 + k;
      float a = 0.f;
      #pragma unroll
      for (int f = 0; f < 64; ++f) a = fmaf(agg[qs][f], dW1[f*HD + h], a);
      h1s[qs][h] = fmaxf(a * inv[qs] + db1[h], 0.f);
    }
  }
  __syncthreads();
  if (t < 48) {
    int qs = t / 3, o = t % 3;
    float a = db2[o];
    #pragma unroll
    for (int h = 0; h < HD; ++h) a = fmaf(h1s[qs][h], dW2[h*3 + o], a);
    out[(qb + qs)*3 + o] = a;
  }
}

extern "C" void kernel_launch(void* const* d_in, const int* in_sizes, int n_in,
                              void* d_out, int out_size, void* d_ws, size_t ws_size,
                              hipStream_t stream) {
  const float* qp   = (const float*)d_in[0];
  const float* nf   = (const float*)d_in[1];
  const float* npos = (const float*)d_in[2];
  const float* aW1  = (const float*)d_in[3];
  const float* ab1  = (const float*)d_in[4];
  const float* aW2  = (const float*)d_in[5];
  const float* ab2  = (const float*)d_in[6];
  const float* dW1  = (const float*)d_in[7];
  const float* db1  = (const float*)d_in[8];
  const float* dW2  = (const float*)d_in[9];
  const float* db2  = (const float*)d_in[10];

  float* ws    = (float*)d_ws;
  float* UT2   = ws + OFF_UT2;
  float* B     = ws + OFF_B;
  float* vu    = ws + OFF_VU;
  float* vb    = ws + OFF_VB;
  float* L     = ws + OFF_L;
  float* pm    = ws + OFF_PM;
  float* part  = ws + OFF_PART;
  float* spart = ws + OFF_SPART;

  hipLaunchKernelGGL(k0_prep, dim3(2576), dim3(256), 0, stream,
                     qp, nf, npos, aW1, ab1, aW2, B, UT2, vu, vb);
  hipLaunchKernelGGL(k2_logits, dim3(16, 64), dim3(256), 0, stream,
                     B, UT2, aW2, ab2, qp, npos, vu, vb, L, pm);
  hipLaunchKernelGGL(k4_agg, dim3(512), dim3(256), 0, stream, L, pm, nf, part, spart);
  hipLaunchKernelGGL(k5_dec, dim3(256), dim3(256), 0, stream,
                     part, spart, dW1, db1, dW2, db2, (float*)d_out);
}

// Round 7
// 99.790 us; speedup vs baseline: 3.3724x; 1.0659x over previous
//
#include <hip/hip_runtime.h>
#include <math.h>

#define QN 4096
#define NN 1024
#define FD 64
#define HD 128

typedef float v2f __attribute__((ext_vector_type(2)));
typedef float v4f __attribute__((ext_vector_type(4)));

// workspace layout (float offsets)
#define OFF_UT4   0                      // UT4 [32 h4][4096 q][4]
#define OFF_B     524288                 // B   [1024 n][128 h]
#define OFF_VU    655360                 // vu  [4096 q]
#define OFF_VB    659456                 // vb  [1024 n]
#define OFF_L     660480                 // L   [1024 n][4096 q]
#define OFF_PM    4854784                // pm  [64 tile][4096 q]
#define OFF_PART  5116928                // part[8 c][4096 q][64 f]
#define OFF_SPART 7214080                // spart[8 c][4096 q]
// end: 7246848 floats = 29.0 MB

// ---------------- K0: fused prep: UT4, B, vb, vu ----------------
__global__ __launch_bounds__(256) void k0_prep(
    const float* __restrict__ qp, const float* __restrict__ nf,
    const float* __restrict__ npos, const float* __restrict__ aW1,
    const float* __restrict__ ab1, const float* __restrict__ aW2,
    float* __restrict__ B, float* __restrict__ UT4,
    float* __restrict__ vu, float* __restrict__ vb) {
  int bid = blockIdx.x, t = threadIdx.x;
  if (bid < 2048) {
    // UT4[h4][q][j]: flat idx = h4*16384 + q*4 + j ; h = h4*4+j
    int idx = bid * 256 + t;
    int j = idx & 3, q = (idx >> 2) & 4095, h4 = idx >> 14;
    int h = h4 * 4 + j;
    float u = qp[q*3+0] * aW1[(FD+0)*HD + h]
            + qp[q*3+1] * aW1[(FD+1)*HD + h]
            + qp[q*3+2] * aW1[(FD+2)*HD + h];
    UT4[idx] = u;
  } else if (bid < 2560) {
    int i2 = (bid - 2048) * 256 + t;
    int n = i2 >> 7, h = i2 & 127;
    float s = ab1[h];
    #pragma unroll
    for (int f = 0; f < FD; ++f) s = fmaf(nf[n*FD+f], aW1[f*HD+h], s);
    s -= npos[n*3+0] * aW1[(FD+0)*HD + h]
       + npos[n*3+1] * aW1[(FD+1)*HD + h]
       + npos[n*3+2] * aW1[(FD+2)*HD + h];
    B[i2] = s;
    float pv = s * aW2[h];
    #pragma unroll
    for (int m = 1; m < 64; m <<= 1) pv += __shfl_xor(pv, m, 64);
    __shared__ float ps[4];
    if ((t & 63) == 0) ps[t >> 6] = pv;
    __syncthreads();
    if (t == 0)   vb[n] = ps[0] + ps[1];
    if (t == 128) vb[n] = ps[2] + ps[3];
  } else {
    int q = (bid - 2560) * 256 + t;
    float q0 = qp[q*3+0], q1 = qp[q*3+1], q2 = qp[q*3+2];
    float acc = 0.f;
    #pragma unroll
    for (int h = 0; h < HD; ++h) {
      float u = q0 * aW1[(FD+0)*HD + h]
              + q1 * aW1[(FD+1)*HD + h]
              + q2 * aW1[(FD+2)*HD + h];
      acc = fmaf(aW2[h], u, acc);
    }
    vu[q] = acc;
  }
}

// ---------------- K2: logits; LDS-B(b128) + x4 U loads + pk_add + abs ----
// tile 256q x 16n; 4 q/lane; wave w -> n-slice [w*4, w*4+4)
// score = 0.5*(vu[q]+vb[n]+sum_h v_h*|b+u|) + ab2; logit = score*w

#define LOADU(dst) { \
  _Pragma("unroll") for (int qq = 0; qq < 4; ++qq) { \
    dst[qq][0] = p0[qq*64]; \
    dst[qq][1] = p1[qq*64]; } \
  p0 += 8192; p1 += 8192; }

#define COMPUTE(u) { \
  _Pragma("unroll") for (int nn = 0; nn < 4; ++nn) { \
    v4f b0 = bsb[(nb + nn)*32]; \
    v4f b1 = bsb[(nb + nn)*32 + 1]; \
    v2f b01 = __builtin_shufflevector(b0, b0, 0, 1); \
    v2f b23 = __builtin_shufflevector(b0, b0, 2, 3); \
    v2f b45 = __builtin_shufflevector(b1, b1, 0, 1); \
    v2f b67 = __builtin_shufflevector(b1, b1, 2, 3); \
    _Pragma("unroll") for (int qq = 0; qq < 4; ++qq) { \
      v2f u01 = __builtin_shufflevector(u[qq][0], u[qq][0], 0, 1); \
      v2f u23 = __builtin_shufflevector(u[qq][0], u[qq][0], 2, 3); \
      v2f u45 = __builtin_shufflevector(u[qq][1], u[qq][1], 0, 1); \
      v2f u67 = __builtin_shufflevector(u[qq][1], u[qq][1], 2, 3); \
      v2f t0, t1, t2, t3; \
      asm("v_pk_add_f32 %0, %1, %2" : "=v"(t0) : "v"(u01), "v"(b01)); \
      asm("v_pk_add_f32 %0, %1, %2" : "=v"(t1) : "v"(u23), "v"(b23)); \
      asm("v_pk_add_f32 %0, %1, %2" : "=v"(t2) : "v"(u45), "v"(b45)); \
      asm("v_pk_add_f32 %0, %1, %2" : "=v"(t3) : "v"(u67), "v"(b67)); \
      float a = acc[qq][nn]; \
      a = fmaf(aw[0], __builtin_fabsf(t0.x), a); \
      a = fmaf(aw[1], __builtin_fabsf(t0.y), a); \
      a = fmaf(aw[2], __builtin_fabsf(t1.x), a); \
      a = fmaf(aw[3], __builtin_fabsf(t1.y), a); \
      a = fmaf(aw[4], __builtin_fabsf(t2.x), a); \
      a = fmaf(aw[5], __builtin_fabsf(t2.y), a); \
      a = fmaf(aw[6], __builtin_fabsf(t3.x), a); \
      a = fmaf(aw[7], __builtin_fabsf(t3.y), a); \
      acc[qq][nn] = a; } } \
  bsb += 2; aw += 8; }

__global__ __launch_bounds__(256) void k2_logits(
    const float* __restrict__ Bg, const float* __restrict__ UT4,
    const float* __restrict__ aW2, const float* __restrict__ ab2,
    const float* __restrict__ qp, const float* __restrict__ npos,
    const float* __restrict__ vu, const float* __restrict__ vb,
    float* __restrict__ L, float* __restrict__ pm) {
  __shared__ float Bs[16 * HD];      // 8 KB
  __shared__ float red[4][4][64];    // 4 KB
  const int q0 = blockIdx.x * 256, n0 = blockIdx.y * 16;
  const int t = threadIdx.x;
  {
    const float4* src = (const float4*)(Bg + n0 * HD);
    float4* dst = (float4*)Bs;
    #pragma unroll
    for (int r = 0; r < 2; ++r) dst[r*256 + t] = src[r*256 + t];
  }
  __syncthreads();
  const int lane = t & 63, w = t >> 6;
  const int nb = w * 4;

  float acc[4][4];
  #pragma unroll
  for (int qq = 0; qq < 4; ++qq)
    #pragma unroll
    for (int nn = 0; nn < 4; ++nn) acc[qq][nn] = 0.f;

  const v4f* p0 = (const v4f*)UT4 + q0 + lane;   // h4 even chunk
  const v4f* p1 = p0 + 4096;                     // h4 odd chunk
  const v4f* bsb = (const v4f*)Bs;
  const float* aw = aW2;

  v4f uA[4][2], uB[4][2];
  LOADU(uA);
  #pragma unroll 1
  for (int hc = 0; hc < 14; hc += 2) {
    LOADU(uB);
    COMPUTE(uA);
    LOADU(uA);
    COMPUTE(uB);
  }
  LOADU(uB);
  COMPUTE(uA);
  COMPUTE(uB);

  const float bias2 = ab2[0];
  float qx[4], qy[4], vuq[4], m4[4];
  #pragma unroll
  for (int qq = 0; qq < 4; ++qq) {
    int q = q0 + qq*64 + lane;
    qx[qq] = qp[q*3+0];
    qy[qq] = qp[q*3+1];
    vuq[qq] = vu[q];
    m4[qq] = -3.4e38f;
  }
  #pragma unroll
  for (int nn = 0; nn < 4; ++nn) {
    int n = n0 + nb + nn;
    float px = npos[n*3+0], py = npos[n*3+1];
    float vbn = vb[n];
    #pragma unroll
    for (int qq = 0; qq < 4; ++qq) {
      float dx = qx[qq] - px, dy = qy[qq] - py;
      float wgt = 1.f / (sqrtf(dx*dx + dy*dy) + 1e-6f);
      float score = fmaf(0.5f, vuq[qq] + vbn + acc[qq][nn], bias2);
      float lg = score * wgt;
      L[n * QN + q0 + qq*64 + lane] = lg;
      m4[qq] = fmaxf(m4[qq], lg);
    }
  }
  #pragma unroll
  for (int qq = 0; qq < 4; ++qq) red[w][qq][lane] = m4[qq];
  __syncthreads();
  {
    int qq = t >> 6, ll = t & 63;
    float mm = fmaxf(fmaxf(red[0][qq][ll], red[1][qq][ll]),
                     fmaxf(red[2][qq][ll], red[3][qq][ll]));
    pm[blockIdx.y * QN + q0 + qq*64 + ll] = mm;
  }
}

// ---------------- K4: exp + partial aggregate; part[c][q][f] ----------------
__global__ __launch_bounds__(256) void k4_agg(
    const float* __restrict__ L, const float* __restrict__ pm,
    const float* __restrict__ nf, float* __restrict__ part,
    float* __restrict__ spart) {
  __shared__ float red[4][32][65];
  __shared__ float sred[4][64];
  int b = blockIdx.x;
  int qt = b & 63, c = b >> 6;        // c in [0,8)
  int t = threadIdx.x, lane = t & 63, w = t >> 6;
  int q = qt * 64 + lane;

  float m = -3.4e38f;
  #pragma unroll
  for (int c64 = 0; c64 < 64; ++c64) m = fmaxf(m, pm[c64 * QN + q]);

  float acc[64];
  #pragma unroll
  for (int f = 0; f < 64; ++f) acc[f] = 0.f;
  float s = 0.f;

  int nbase = c * 128 + w * 32;
  float cur = L[nbase * QN + q];
  for (int i = 0; i < 32; ++i) {
    int n = nbase + i;
    float nxt = (i < 31) ? L[(n + 1) * QN + q] : 0.f;
    float p = exp2f((cur - m) * 1.44269504088896f);
    s += p;
    const float4* nfr = (const float4*)(nf + n * FD);
    #pragma unroll
    for (int g = 0; g < 4; ++g) {
      float4 a0 = nfr[g*4+0], a1 = nfr[g*4+1], a2 = nfr[g*4+2], a3 = nfr[g*4+3];
      acc[g*16+ 0] = fmaf(p, a0.x, acc[g*16+ 0]);
      acc[g*16+ 1] = fmaf(p, a0.y, acc[g*16+ 1]);
      acc[g*16+ 2] = fmaf(p, a0.z, acc[g*16+ 2]);
      acc[g*16+ 3] = fmaf(p, a0.w, acc[g*16+ 3]);
      acc[g*16+ 4] = fmaf(p, a1.x, acc[g*16+ 4]);
      acc[g*16+ 5] = fmaf(p, a1.y, acc[g*16+ 5]);
      acc[g*16+ 6] = fmaf(p, a1.z, acc[g*16+ 6]);
      acc[g*16+ 7] = fmaf(p, a1.w, acc[g*16+ 7]);
      acc[g*16+ 8] = fmaf(p, a2.x, acc[g*16+ 8]);
      acc[g*16+ 9] = fmaf(p, a2.y, acc[g*16+ 9]);
      acc[g*16+10] = fmaf(p, a2.z, acc[g*16+10]);
      acc[g*16+11] = fmaf(p, a2.w, acc[g*16+11]);
      acc[g*16+12] = fmaf(p, a3.x, acc[g*16+12]);
      acc[g*16+13] = fmaf(p, a3.y, acc[g*16+13]);
      acc[g*16+14] = fmaf(p, a3.z, acc[g*16+14]);
      acc[g*16+15] = fmaf(p, a3.w, acc[g*16+15]);
    }
    cur = nxt;
  }

  sred[w][lane] = s;
  #pragma unroll
  for (int f = 0; f < 32; ++f) red[w][f][lane] = acc[f];
  __syncthreads();
  for (int idx = t; idx < 2048; idx += 256) {
    int qq = idx >> 5, fr = idx & 31;
    float sum = red[0][fr][qq] + red[1][fr][qq] + red[2][fr][qq] + red[3][fr][qq];
    part[(c * QN + qt*64 + qq) * 64 + fr] = sum;
  }
  __syncthreads();
  #pragma unroll
  for (int f = 0; f < 32; ++f) red[w][f][lane] = acc[32 + f];
  __syncthreads();
  for (int idx = t; idx < 2048; idx += 256) {
    int qq = idx >> 5, fr = idx & 31;
    float sum = red[0][fr][qq] + red[1][fr][qq] + red[2][fr][qq] + red[3][fr][qq];
    part[(c * QN + qt*64 + qq) * 64 + 32 + fr] = sum;
  }
  __syncthreads();
  if (t < 64) {
    spart[c * QN + qt*64 + t] = sred[0][t] + sred[1][t] + sred[2][t] + sred[3][t];
  }
}

// ---------------- K5: reduce partials, normalize, decode ----------------
__global__ __launch_bounds__(256) void k5_dec(
    const float* __restrict__ part, const float* __restrict__ spart,
    const float* __restrict__ dW1, const float* __restrict__ db1,
    const float* __restrict__ dW2, const float* __restrict__ db2,
    float* __restrict__ out) {
  __shared__ float agg[16][64];
  __shared__ float inv[16];
  __shared__ float h1s[16][128];
  int t = threadIdx.x;
  int qb = blockIdx.x * 16;
  if (t < 16) {
    float s = 0.f;
    #pragma unroll
    for (int c = 0; c < 8; ++c) s += spart[c*QN + qb + t];
    inv[t] = 1.f / s;
  }
  {
    int f = t & 63, qh = t >> 6;
    #pragma unroll
    for (int pass = 0; pass < 4; ++pass) {
      int qs = pass*4 + qh;
      float v = 0.f;
      #pragma unroll
      for (int c = 0; c < 8; ++c) v += part[(c*QN + qb + qs)*64 + f];
      agg[qs][f] = v;
    }
  }
  __syncthreads();
  {
    int h = t & 127, qg = t >> 7;
    #pragma unroll
    for (int k = 0; k < 8; ++k) {
      int qs = qg*8 + k;
      float a = 0.f;
      #pragma unroll
      for (int f = 0; f < 64; ++f) a = fmaf(agg[qs][f], dW1[f*HD + h], a);
      h1s[qs][h] = fmaxf(a * inv[qs] + db1[h], 0.f);
    }
  }
  __syncthreads();
  if (t < 48) {
    int qs = t / 3, o = t % 3;
    float a = db2[o];
    #pragma unroll
    for (int h = 0; h < HD; ++h) a = fmaf(h1s[qs][h], dW2[h*3 + o], a);
    out[(qb + qs)*3 + o] = a;
  }
}

extern "C" void kernel_launch(void* const* d_in, const int* in_sizes, int n_in,
                              void* d_out, int out_size, void* d_ws, size_t ws_size,
                              hipStream_t stream) {
  const float* qp   = (const float*)d_in[0];
  const float* nf   = (const float*)d_in[1];
  const float* npos = (const float*)d_in[2];
  const float* aW1  = (const float*)d_in[3];
  const float* ab1  = (const float*)d_in[4];
  const float* aW2  = (const float*)d_in[5];
  const float* ab2  = (const float*)d_in[6];
  const float* dW1  = (const float*)d_in[7];
  const float* db1  = (const float*)d_in[8];
  const float* dW2  = (const float*)d_in[9];
  const float* db2  = (const float*)d_in[10];

  float* ws    = (float*)d_ws;
  float* UT4   = ws + OFF_UT4;
  float* B     = ws + OFF_B;
  float* vu    = ws + OFF_VU;
  float* vb    = ws + OFF_VB;
  float* L     = ws + OFF_L;
  float* pm    = ws + OFF_PM;
  float* part  = ws + OFF_PART;
  float* spart = ws + OFF_SPART;

  hipLaunchKernelGGL(k0_prep, dim3(2576), dim3(256), 0, stream,
                     qp, nf, npos, aW1, ab1, aW2, B, UT4, vu, vb);
  hipLaunchKernelGGL(k2_logits, dim3(16, 64), dim3(256), 0, stream,
                     B, UT4, aW2, ab2, qp, npos, vu, vb, L, pm);
  hipLaunchKernelGGL(k4_agg, dim3(512), dim3(256), 0, stream, L, pm, nf, part, spart);
  hipLaunchKernelGGL(k5_dec, dim3(256), dim3(256), 0, stream,
                     part, spart, dW1, db1, dW2, db2, (float*)d_out);
}